// Round 5
// baseline (417.899 us; speedup 1.0000x reference)
//
#include <hip/hip_runtime.h>

// ---------------------------------------------------------------------------
// GCN block: 3x (GEMM -> degree-normalized aggregate), residual, relu.
//   norm(src,dst) = dinv[src]*dinv[dst]; dinv[src] folded into GEMM epilogue,
//   dinv[dst] folded into aggregation epilogue.
//   hs (the gathered tensor) is stored bf16 -> halves the random-gather bytes.
// CSR build: bucket partition by dst>>8 (packed src<<8|dst&255), then
//   per-bucket LDS counting sort -> node CSR col[] in a contiguous L2-resident
//   window, row_ptr + dinv for free. Raw edge_index read with flag-dependent
//   stride (int64 vs int32), no conversion pass.
// GEMM: 128-row x 64-col blocks (782 blocks -> 3-5 resident/CU), thread tile
//   8x4, A read directly from global as float4 (16-lane address sharing ->
//   coalesced broadcast), only W staged in LDS. No per-chunk syncthreads.
// Aggregation: one wave per node, lane = feature col, indices via __shfl.
// ---------------------------------------------------------------------------

#define LB 8                    // low bits: 256 nodes per bucket
#define BKN 256                 // nodes per bucket
#define CHUNK 8192              // edges per scatter block

typedef unsigned short ushort_t;

__device__ __forceinline__ unsigned f2bf(float f) {
    unsigned u = __builtin_bit_cast(unsigned, f);
    return (u + 0x7FFFu + ((u >> 16) & 1u)) >> 16;   // RNE
}
__device__ __forceinline__ float bf2f(ushort_t h) {
    unsigned u = ((unsigned)h) << 16;
    return __builtin_bit_cast(float, u);
}

// ---- edge dtype detection (int64 vs int32), sampled -----------------------
__global__ void detect64_kernel(const unsigned int* __restrict__ raw, int nwords,
                                int* __restrict__ flag) {
    int i = blockIdx.x * blockDim.x + threadIdx.x;
    if (i < nwords && (i & 1) && raw[i] != 0u) flag[0] = 0; // benign race
}

// ---- bucket histogram (reads raw dst) -------------------------------------
__global__ __launch_bounds__(256) void bucket_hist_kernel(
        const int* __restrict__ raw, int E, const int* __restrict__ flag,
        int* __restrict__ bucketCounts, int B) {
    __shared__ int h[512];
    for (int i = threadIdx.x; i < 512; i += 256) h[i] = 0;
    __syncthreads();
    int f = flag[0];
    int stride = gridDim.x * blockDim.x;
    for (int e = blockIdx.x * blockDim.x + threadIdx.x; e < E; e += stride) {
        int d = f ? raw[2 * (E + e)] : raw[E + e];
        atomicAdd(&h[d >> LB], 1);
    }
    __syncthreads();
    for (int i = threadIdx.x; i < B; i += 256)
        if (h[i]) atomicAdd(&bucketCounts[i], h[i]);
}

// ---- bucket exclusive scan (B <= 512), writes offs + cursor copy ----------
__global__ __launch_bounds__(512) void bucket_scan_kernel(
        const int* __restrict__ counts, int* __restrict__ offs,
        int* __restrict__ cursor, int B) {
    __shared__ int s[512];
    int tid = threadIdx.x;
    int v = (tid < B) ? counts[tid] : 0;
    s[tid] = v;
    __syncthreads();
    for (int off = 1; off < 512; off <<= 1) {
        int x = (tid >= off) ? s[tid - off] : 0;
        __syncthreads();
        if (tid >= off) s[tid] += x;
        __syncthreads();
    }
    if (tid < B) { int e = s[tid] - v; offs[tid] = e; cursor[tid] = e; }
    if (tid == B - 1) offs[B] = s[tid];
}

// ---- partition edges into bucket regions as packed (src<<8 | dst&255) -----
__global__ __launch_bounds__(256) void bucket_scatter_kernel(
        const int* __restrict__ raw, const int* __restrict__ flag,
        int* __restrict__ bucketCursor, unsigned int* __restrict__ packed, int E) {
    __shared__ int hist[512];
    __shared__ int base[512];
    int f = flag[0];
    int b0 = blockIdx.x * CHUNK;
    int n = min(CHUNK, E - b0);
    for (int i = threadIdx.x; i < 512; i += 256) hist[i] = 0;
    __syncthreads();
    for (int i = threadIdx.x; i < n; i += 256) {
        int e = b0 + i;
        int d = f ? raw[2 * (E + e)] : raw[E + e];
        atomicAdd(&hist[d >> LB], 1);
    }
    __syncthreads();
    for (int i = threadIdx.x; i < 512; i += 256) {
        int c = hist[i];
        base[i] = c ? atomicAdd(&bucketCursor[i], c) : 0;
        hist[i] = 0;
    }
    __syncthreads();
    for (int i = threadIdx.x; i < n; i += 256) {
        int e = b0 + i;
        int d = f ? raw[2 * (E + e)] : raw[E + e];
        int s = f ? raw[2 * e] : raw[e];
        int bk = d >> LB;
        int pos = base[bk] + atomicAdd(&hist[bk], 1);
        packed[pos] = ((unsigned)s << LB) | (unsigned)(d & (BKN - 1));
    }
}

// ---- per-bucket counting sort: packed -> CSR col[], row_ptr, dinv ---------
__global__ __launch_bounds__(256) void sort_kernel(
        const unsigned int* __restrict__ packed, const int* __restrict__ offs,
        int* __restrict__ col, int* __restrict__ row_ptr, float* __restrict__ dinv,
        int N, int E) {
    __shared__ int hist[BKN];
    __shared__ int s[BKN];
    __shared__ int cur[BKN];
    int tid = threadIdx.x;
    int b = blockIdx.x;
    int start = offs[b], end = offs[b + 1];
    hist[tid] = 0;
    __syncthreads();
    for (int e = start + tid; e < end; e += 256)
        atomicAdd(&hist[packed[e] & (BKN - 1)], 1);
    __syncthreads();
    int v = hist[tid];
    s[tid] = v;
    __syncthreads();
    for (int off = 1; off < 256; off <<= 1) {
        int x = (tid >= off) ? s[tid - off] : 0;
        __syncthreads();
        if (tid >= off) s[tid] += x;
        __syncthreads();
    }
    int excl = s[tid] - v;
    cur[tid] = start + excl;
    int node = (b << LB) + tid;
    if (node < N) {
        row_ptr[node] = start + excl;
        dinv[node] = rsqrtf((float)(v + 1));   // +1 self loop
    }
    if (b == 0 && tid == 0) row_ptr[N] = E;
    __syncthreads();
    for (int e = start + tid; e < end; e += 256) {
        unsigned pv = packed[e];
        int pos = atomicAdd(&cur[pv & (BKN - 1)], 1);
        col[pos] = (int)(pv >> LB);
    }
}

// ---- GEMM (N x K) @ (K x 64), epilogue-scaled by dinv[row], bf16 out ------
// 128 rows x 64 cols per block, 256 threads, thread tile 8 rows x 4 cols.
// A read directly from global (float4 along K); within each 16-lane group the
// addresses coincide -> coalescer collapses to 4x16B segments per load instr.
// Only W is LDS-staged (32KB K=128 / 16KB K=64) -> 4-5 blocks/CU resident.
template <int K>
__global__ __launch_bounds__(256) void gemm_scaled_kernel(
        const float* __restrict__ A, const float* __restrict__ W,
        const float* __restrict__ dinv, ushort_t* __restrict__ out, int nrows) {
    __shared__ float sW[K * 64];
    int tid = threadIdx.x;
    int rowBase = blockIdx.x * 128;
    for (int i = tid * 4; i < K * 64; i += 1024)
        *(float4*)&sW[i] = *(const float4*)&W[i];
    __syncthreads();

    int c0 = (tid & 15) * 4;        // col group
    int r0 = (tid >> 4) * 8;        // row group

    const float* ap[8];
#pragma unroll
    for (int i = 0; i < 8; i++) {
        int grow = rowBase + r0 + i;
        if (grow >= nrows) grow = nrows - 1;
        ap[i] = A + (size_t)grow * K;
    }

    float acc[8][4];
#pragma unroll
    for (int i = 0; i < 8; i++)
#pragma unroll
        for (int c = 0; c < 4; c++) acc[i][c] = 0.f;

    for (int k = 0; k < K; k += 4) {
        float4 a[8];
#pragma unroll
        for (int i = 0; i < 8; i++) a[i] = *(const float4*)(ap[i] + k);
        float4 w0 = *(float4*)&sW[(k + 0) * 64 + c0];
        float4 w1 = *(float4*)&sW[(k + 1) * 64 + c0];
        float4 w2 = *(float4*)&sW[(k + 2) * 64 + c0];
        float4 w3 = *(float4*)&sW[(k + 3) * 64 + c0];
#pragma unroll
        for (int i = 0; i < 8; i++) {
            acc[i][0] = fmaf(a[i].x, w0.x, acc[i][0]);
            acc[i][1] = fmaf(a[i].x, w0.y, acc[i][1]);
            acc[i][2] = fmaf(a[i].x, w0.z, acc[i][2]);
            acc[i][3] = fmaf(a[i].x, w0.w, acc[i][3]);
            acc[i][0] = fmaf(a[i].y, w1.x, acc[i][0]);
            acc[i][1] = fmaf(a[i].y, w1.y, acc[i][1]);
            acc[i][2] = fmaf(a[i].y, w1.z, acc[i][2]);
            acc[i][3] = fmaf(a[i].y, w1.w, acc[i][3]);
            acc[i][0] = fmaf(a[i].z, w2.x, acc[i][0]);
            acc[i][1] = fmaf(a[i].z, w2.y, acc[i][1]);
            acc[i][2] = fmaf(a[i].z, w2.z, acc[i][2]);
            acc[i][3] = fmaf(a[i].z, w2.w, acc[i][3]);
            acc[i][0] = fmaf(a[i].w, w3.x, acc[i][0]);
            acc[i][1] = fmaf(a[i].w, w3.y, acc[i][1]);
            acc[i][2] = fmaf(a[i].w, w3.z, acc[i][2]);
            acc[i][3] = fmaf(a[i].w, w3.w, acc[i][3]);
        }
    }

#pragma unroll
    for (int i = 0; i < 8; i++) {
        int grow = rowBase + r0 + i;
        if (grow < nrows) {
            float sc = dinv[grow];
            uint2 o;
            o.x = f2bf(acc[i][0] * sc) | (f2bf(acc[i][1] * sc) << 16);
            o.y = f2bf(acc[i][2] * sc) | (f2bf(acc[i][3] * sc) << 16);
            *(uint2*)&out[(size_t)grow * 64 + c0] = o;
        }
    }
}

// ---- aggregation: one wave per node, lane = feature column ----------------
// out[n] = dinv[n] * (hs[n] + sum_{e in adj(n)} hs[col[e]]) + bias
// hs is bf16 (128B/row gather); accumulation in f32.
__global__ __launch_bounds__(256) void aggregate_kernel(
        const ushort_t* __restrict__ hs, const float* __restrict__ dinv,
        const float* __restrict__ bias, const int* __restrict__ col,
        const int* __restrict__ row_ptr, const float* __restrict__ resid,
        float* __restrict__ out, int n, int relu) {
    int wave = (blockIdx.x * blockDim.x + threadIdx.x) >> 6;
    int lane = threadIdx.x & 63;
    if (wave >= n) return;
    int start = row_ptr[wave];
    int end = row_ptr[wave + 1];
    float acc = bf2f(hs[(size_t)wave * 64 + lane]); // self-loop (pre-scaled)
    int e = start;
    while (e < end) {
        int cnt = end - e;
        if (cnt > 64) cnt = 64;
        int myidx = (lane < cnt) ? col[e + lane] : 0;
        int j = 0;
        for (; j + 8 <= cnt; j += 8) {
            int s0 = __shfl(myidx, j + 0);
            int s1 = __shfl(myidx, j + 1);
            int s2 = __shfl(myidx, j + 2);
            int s3 = __shfl(myidx, j + 3);
            int s4 = __shfl(myidx, j + 4);
            int s5 = __shfl(myidx, j + 5);
            int s6 = __shfl(myidx, j + 6);
            int s7 = __shfl(myidx, j + 7);
            ushort_t u0 = hs[(size_t)s0 * 64 + lane];
            ushort_t u1 = hs[(size_t)s1 * 64 + lane];
            ushort_t u2 = hs[(size_t)s2 * 64 + lane];
            ushort_t u3 = hs[(size_t)s3 * 64 + lane];
            ushort_t u4 = hs[(size_t)s4 * 64 + lane];
            ushort_t u5 = hs[(size_t)s5 * 64 + lane];
            ushort_t u6 = hs[(size_t)s6 * 64 + lane];
            ushort_t u7 = hs[(size_t)s7 * 64 + lane];
            acc += bf2f(u0) + bf2f(u1) + bf2f(u2) + bf2f(u3)
                 + bf2f(u4) + bf2f(u5) + bf2f(u6) + bf2f(u7);
        }
        for (; j < cnt; j++) {
            int s = __shfl(myidx, j);
            acc += bf2f(hs[(size_t)s * 64 + lane]);
        }
        e += cnt;
    }
    float o = dinv[wave] * acc + bias[lane];
    if (relu) o = fmaxf(o, 0.f);
    if (resid) o += resid[(size_t)wave * 64 + lane];
    out[(size_t)wave * 64 + lane] = o;
}

// ---------------------------------------------------------------------------
extern "C" void kernel_launch(void* const* d_in, const int* in_sizes, int n_in,
                              void* d_out, int out_size, void* d_ws, size_t ws_size,
                              hipStream_t stream) {
    const float* x  = (const float*)d_in[0];
    const int*   ei = (const int*)d_in[1];
    const float* W0 = (const float*)d_in[2];
    const float* b0 = (const float*)d_in[3];
    const float* Ws = (const float*)d_in[4];
    const float* bs = (const float*)d_in[5];
    float* out = (float*)d_out;

    const int N = in_sizes[0] / 128;
    const int E = in_sizes[1] / 2;
    const int B = (N + BKN - 1) >> LB;   // 391 buckets for N=100k

    char* p = (char*)d_ws;
    auto carve = [&](size_t bytes) {
        char* r = p;
        p += (bytes + 255) & ~(size_t)255;
        return r;
    };
    int*      flag         = (int*)carve(4);
    int*      bucketCounts = (int*)carve(512 * 4);
    int*      bucketOffs   = (int*)carve(513 * 4);
    int*      bucketCursor = (int*)carve(512 * 4);
    unsigned* packed       = (unsigned*)carve((size_t)E * 4);
    int*      col          = (int*)carve((size_t)E * 4);
    int*      row_ptr      = (int*)carve((size_t)(N + 1) * 4);
    float*    dinv         = (float*)carve((size_t)N * 4);
    ushort_t* hs           = (ushort_t*)carve((size_t)N * 64 * 2);
    float*    xt           = (float*)carve((size_t)N * 64 * 4);
    float*    h            = (float*)carve((size_t)N * 64 * 4);

    hipMemsetAsync(flag, 1, 4, stream);              // nonzero = "int64"
    hipMemsetAsync(bucketCounts, 0, 512 * 4, stream);

    int dwords = min(2 * E, 65536);                  // sampled dtype probe
    detect64_kernel<<<(dwords + 255) / 256, 256, 0, stream>>>(
        (const unsigned int*)ei, dwords, flag);

    bucket_hist_kernel<<<512, 256, 0, stream>>>(ei, E, flag, bucketCounts, B);
    bucket_scan_kernel<<<1, 512, 0, stream>>>(bucketCounts, bucketOffs, bucketCursor, B);
    bucket_scatter_kernel<<<(E + CHUNK - 1) / CHUNK, 256, 0, stream>>>(
        ei, flag, bucketCursor, packed, E);
    sort_kernel<<<B, 256, 0, stream>>>(packed, bucketOffs, col, row_ptr, dinv, N, E);

    int gblocks = (N + 127) / 128;
    int ablocks = (N + 3) / 4;
    // layer 1: x_temp = agg(x @ W0) + b0            (no relu)
    gemm_scaled_kernel<128><<<gblocks, 256, 0, stream>>>(x, W0, dinv, hs, N);
    aggregate_kernel<<<ablocks, 256, 0, stream>>>(hs, dinv, b0, col, row_ptr, nullptr, xt, N, 0);
    // layer 2: h = relu(agg(xt @ Ws[0]) + bs[0])
    gemm_scaled_kernel<64><<<gblocks, 256, 0, stream>>>(xt, Ws, dinv, hs, N);
    aggregate_kernel<<<ablocks, 256, 0, stream>>>(hs, dinv, bs, col, row_ptr, nullptr, h, N, 1);
    // layer 3: out = relu(agg(h @ Ws[1]) + bs[1]) + xt
    gemm_scaled_kernel<64><<<gblocks, 256, 0, stream>>>(h, Ws + 64 * 64, dinv, hs, N);
    aggregate_kernel<<<ablocks, 256, 0, stream>>>(hs, dinv, bs + 64, col, row_ptr, xt, out, N, 1);
}

// Round 6
// 362.890 us; speedup vs baseline: 1.1516x; 1.1516x over previous
//
#include <hip/hip_runtime.h>

// ---------------------------------------------------------------------------
// GCN block: 3x (MFMA bf16 GEMM -> degree-normalized aggregate), resid, relu.
//   norm(src,dst) = dinv[src]*dinv[dst]; dinv[src] folded into GEMM epilogue,
//   dinv[dst] folded into aggregation epilogue.
//   All node tensors between stages are bf16 (halves gather + GEMM traffic);
//   f32 kept only for the residual copy (xt) and the final output.
// CSR build: bucket partition by dst>>8 (packed src<<8|dst&255), then
//   per-bucket LDS counting sort -> node CSR col[], row_ptr, dinv.
// GEMM: v_mfma_f32_16x16x32_bf16. Block = 4 waves x (32 rows x 64 cols);
//   W^T bf16 in LDS (pad +8 -> 2-way bank alias = free); A frags direct from
//   global (layer1 cvt f32->bf16 in flight, layers 2/3 already bf16).
// Aggregation: one wave per node, lane = feature col, indices via __shfl;
//   writes f32 and/or bf16 outputs.
// ---------------------------------------------------------------------------

#define LB 8                    // low bits: 256 nodes per bucket
#define BKN 256                 // nodes per bucket
#define CHUNK 8192              // edges per scatter block

typedef unsigned short ushort_t;
typedef __attribute__((ext_vector_type(8))) short bf16x8;
typedef __attribute__((ext_vector_type(4))) float f32x4;

__device__ __forceinline__ unsigned f2bf(float f) {
    unsigned u = __builtin_bit_cast(unsigned, f);
    return (u + 0x7FFFu + ((u >> 16) & 1u)) >> 16;   // RNE
}
__device__ __forceinline__ float bf2f(ushort_t h) {
    unsigned u = ((unsigned)h) << 16;
    return __builtin_bit_cast(float, u);
}

// ---- edge dtype detection (int64 vs int32), sampled -----------------------
__global__ void detect64_kernel(const unsigned int* __restrict__ raw, int nwords,
                                int* __restrict__ flag) {
    int i = blockIdx.x * blockDim.x + threadIdx.x;
    if (i < nwords && (i & 1) && raw[i] != 0u) flag[0] = 0; // benign race
}

// ---- bucket histogram (reads raw dst) -------------------------------------
__global__ __launch_bounds__(256) void bucket_hist_kernel(
        const int* __restrict__ raw, int E, const int* __restrict__ flag,
        int* __restrict__ bucketCounts, int B) {
    __shared__ int h[512];
    for (int i = threadIdx.x; i < 512; i += 256) h[i] = 0;
    __syncthreads();
    int f = flag[0];
    int stride = gridDim.x * blockDim.x;
    for (int e = blockIdx.x * blockDim.x + threadIdx.x; e < E; e += stride) {
        int d = f ? raw[2 * (E + e)] : raw[E + e];
        atomicAdd(&h[d >> LB], 1);
    }
    __syncthreads();
    for (int i = threadIdx.x; i < B; i += 256)
        if (h[i]) atomicAdd(&bucketCounts[i], h[i]);
}

// ---- bucket exclusive scan (B <= 512), writes offs + cursor copy ----------
__global__ __launch_bounds__(512) void bucket_scan_kernel(
        const int* __restrict__ counts, int* __restrict__ offs,
        int* __restrict__ cursor, int B) {
    __shared__ int s[512];
    int tid = threadIdx.x;
    int v = (tid < B) ? counts[tid] : 0;
    s[tid] = v;
    __syncthreads();
    for (int off = 1; off < 512; off <<= 1) {
        int x = (tid >= off) ? s[tid - off] : 0;
        __syncthreads();
        if (tid >= off) s[tid] += x;
        __syncthreads();
    }
    if (tid < B) { int e = s[tid] - v; offs[tid] = e; cursor[tid] = e; }
    if (tid == B - 1) offs[B] = s[tid];
}

// ---- partition edges into bucket regions as packed (src<<8 | dst&255) -----
__global__ __launch_bounds__(256) void bucket_scatter_kernel(
        const int* __restrict__ raw, const int* __restrict__ flag,
        int* __restrict__ bucketCursor, unsigned int* __restrict__ packed, int E) {
    __shared__ int hist[512];
    __shared__ int base[512];
    int f = flag[0];
    int b0 = blockIdx.x * CHUNK;
    int n = min(CHUNK, E - b0);
    for (int i = threadIdx.x; i < 512; i += 256) hist[i] = 0;
    __syncthreads();
    for (int i = threadIdx.x; i < n; i += 256) {
        int e = b0 + i;
        int d = f ? raw[2 * (E + e)] : raw[E + e];
        atomicAdd(&hist[d >> LB], 1);
    }
    __syncthreads();
    for (int i = threadIdx.x; i < 512; i += 256) {
        int c = hist[i];
        base[i] = c ? atomicAdd(&bucketCursor[i], c) : 0;
        hist[i] = 0;
    }
    __syncthreads();
    for (int i = threadIdx.x; i < n; i += 256) {
        int e = b0 + i;
        int d = f ? raw[2 * (E + e)] : raw[E + e];
        int s = f ? raw[2 * e] : raw[e];
        int bk = d >> LB;
        int pos = base[bk] + atomicAdd(&hist[bk], 1);
        packed[pos] = ((unsigned)s << LB) | (unsigned)(d & (BKN - 1));
    }
}

// ---- per-bucket counting sort: packed -> CSR col[], row_ptr, dinv ---------
__global__ __launch_bounds__(256) void sort_kernel(
        const unsigned int* __restrict__ packed, const int* __restrict__ offs,
        int* __restrict__ col, int* __restrict__ row_ptr, float* __restrict__ dinv,
        int N, int E) {
    __shared__ int hist[BKN];
    __shared__ int s[BKN];
    __shared__ int cur[BKN];
    int tid = threadIdx.x;
    int b = blockIdx.x;
    int start = offs[b], end = offs[b + 1];
    hist[tid] = 0;
    __syncthreads();
    for (int e = start + tid; e < end; e += 256)
        atomicAdd(&hist[packed[e] & (BKN - 1)], 1);
    __syncthreads();
    int v = hist[tid];
    s[tid] = v;
    __syncthreads();
    for (int off = 1; off < 256; off <<= 1) {
        int x = (tid >= off) ? s[tid - off] : 0;
        __syncthreads();
        if (tid >= off) s[tid] += x;
        __syncthreads();
    }
    int excl = s[tid] - v;
    cur[tid] = start + excl;
    int node = (b << LB) + tid;
    if (node < N) {
        row_ptr[node] = start + excl;
        dinv[node] = rsqrtf((float)(v + 1));   // +1 self loop
    }
    if (b == 0 && tid == 0) row_ptr[N] = E;
    __syncthreads();
    for (int e = start + tid; e < end; e += 256) {
        unsigned pv = packed[e];
        int pos = atomicAdd(&cur[pv & (BKN - 1)], 1);
        col[pos] = (int)(pv >> LB);
    }
}

// ---- MFMA GEMM (N x K) @ (K x 64), epilogue dinv-scale, bf16 out ----------
// Block: 256 thr = 4 waves; wave computes 32 rows x 64 cols via
// v_mfma_f32_16x16x32_bf16 tiles (2 row-tiles x 4 col-tiles).
// A frag layout: A[m=lane&15][k=quad*8+j]; B frag: B[k=quad*8+j][n=lane&15];
// C/D: col=lane&15, row=quad*4+reg (measured, learn_hip m89/m91).
template <int K, bool AF32>
__global__ __launch_bounds__(256) void gemm_mfma_kernel(
        const void* __restrict__ Av, const float* __restrict__ W,
        const float* __restrict__ dinv, ushort_t* __restrict__ out, int nrows) {
    __shared__ ushort_t sWT[64 * (K + 8)];     // W^T bf16, pad 8 -> free 2-way
    int tid = threadIdx.x;
    for (int i = tid; i < K * 64; i += 256) {
        int n = i & 63, k = i >> 6;
        sWT[n * (K + 8) + k] = (ushort_t)f2bf(W[i]);
    }
    __syncthreads();

    int wave = tid >> 6, lane = tid & 63;
    int quad = lane >> 4, l16 = lane & 15;
    int rowBase = blockIdx.x * 128 + wave * 32;

    f32x4 acc[2][4];
#pragma unroll
    for (int r = 0; r < 2; r++)
#pragma unroll
        for (int c = 0; c < 4; c++) acc[r][c] = (f32x4){0.f, 0.f, 0.f, 0.f};

#pragma unroll
    for (int chunk = 0; chunk < K / 32; chunk++) {
        bf16x8 afr[2];
#pragma unroll
        for (int r = 0; r < 2; r++) {
            int row = rowBase + r * 16 + l16;
            if (row >= nrows) row = nrows - 1;
            if (AF32) {
                const float* ap = (const float*)Av + (size_t)row * K + chunk * 32 + quad * 8;
                float4 v0 = *(const float4*)ap;
                float4 v1 = *(const float4*)(ap + 4);
                bf16x8 a;
                a[0] = (short)f2bf(v0.x); a[1] = (short)f2bf(v0.y);
                a[2] = (short)f2bf(v0.z); a[3] = (short)f2bf(v0.w);
                a[4] = (short)f2bf(v1.x); a[5] = (short)f2bf(v1.y);
                a[6] = (short)f2bf(v1.z); a[7] = (short)f2bf(v1.w);
                afr[r] = a;
            } else {
                const ushort_t* ap = (const ushort_t*)Av + (size_t)row * K + chunk * 32 + quad * 8;
                afr[r] = __builtin_bit_cast(bf16x8, *(const uint4*)ap);
            }
        }
#pragma unroll
        for (int c = 0; c < 4; c++) {
            bf16x8 bfr = __builtin_bit_cast(
                bf16x8,
                *(const uint4*)&sWT[(c * 16 + l16) * (K + 8) + chunk * 32 + quad * 8]);
#pragma unroll
            for (int r = 0; r < 2; r++)
                acc[r][c] = __builtin_amdgcn_mfma_f32_16x16x32_bf16(
                    afr[r], bfr, acc[r][c], 0, 0, 0);
        }
    }

#pragma unroll
    for (int r = 0; r < 2; r++) {
#pragma unroll
        for (int i = 0; i < 4; i++) {
            int row = rowBase + r * 16 + quad * 4 + i;
            if (row < nrows) {
                float sc = dinv[row];
#pragma unroll
                for (int c = 0; c < 4; c++)
                    out[(size_t)row * 64 + c * 16 + l16] =
                        (ushort_t)f2bf(acc[r][c][i] * sc);
            }
        }
    }
}

// ---- aggregation: one wave per node, lane = feature column ----------------
// o = dinv[n]*(hs[n] + sum hs[col[e]]) + bias (+relu,+resid);
// writes f32 (outf) and/or bf16 (outb).
__global__ __launch_bounds__(256) void aggregate_kernel(
        const ushort_t* __restrict__ hs, const float* __restrict__ dinv,
        const float* __restrict__ bias, const int* __restrict__ col,
        const int* __restrict__ row_ptr, const float* __restrict__ resid,
        float* __restrict__ outf, ushort_t* __restrict__ outb, int n, int relu) {
    int wave = (blockIdx.x * blockDim.x + threadIdx.x) >> 6;
    int lane = threadIdx.x & 63;
    if (wave >= n) return;
    int start = row_ptr[wave];
    int end = row_ptr[wave + 1];
    float acc = bf2f(hs[(size_t)wave * 64 + lane]); // self-loop (pre-scaled)
    int e = start;
    while (e < end) {
        int cnt = end - e;
        if (cnt > 64) cnt = 64;
        int myidx = (lane < cnt) ? col[e + lane] : 0;
        int j = 0;
        for (; j + 8 <= cnt; j += 8) {
            int s0 = __shfl(myidx, j + 0);
            int s1 = __shfl(myidx, j + 1);
            int s2 = __shfl(myidx, j + 2);
            int s3 = __shfl(myidx, j + 3);
            int s4 = __shfl(myidx, j + 4);
            int s5 = __shfl(myidx, j + 5);
            int s6 = __shfl(myidx, j + 6);
            int s7 = __shfl(myidx, j + 7);
            ushort_t u0 = hs[(size_t)s0 * 64 + lane];
            ushort_t u1 = hs[(size_t)s1 * 64 + lane];
            ushort_t u2 = hs[(size_t)s2 * 64 + lane];
            ushort_t u3 = hs[(size_t)s3 * 64 + lane];
            ushort_t u4 = hs[(size_t)s4 * 64 + lane];
            ushort_t u5 = hs[(size_t)s5 * 64 + lane];
            ushort_t u6 = hs[(size_t)s6 * 64 + lane];
            ushort_t u7 = hs[(size_t)s7 * 64 + lane];
            acc += bf2f(u0) + bf2f(u1) + bf2f(u2) + bf2f(u3)
                 + bf2f(u4) + bf2f(u5) + bf2f(u6) + bf2f(u7);
        }
        for (; j < cnt; j++) {
            int s = __shfl(myidx, j);
            acc += bf2f(hs[(size_t)s * 64 + lane]);
        }
        e += cnt;
    }
    float o = dinv[wave] * acc + bias[lane];
    if (relu) o = fmaxf(o, 0.f);
    if (resid) o += resid[(size_t)wave * 64 + lane];
    if (outf) outf[(size_t)wave * 64 + lane] = o;
    if (outb) outb[(size_t)wave * 64 + lane] = (ushort_t)f2bf(o);
}

// ---------------------------------------------------------------------------
extern "C" void kernel_launch(void* const* d_in, const int* in_sizes, int n_in,
                              void* d_out, int out_size, void* d_ws, size_t ws_size,
                              hipStream_t stream) {
    const float* x  = (const float*)d_in[0];
    const int*   ei = (const int*)d_in[1];
    const float* W0 = (const float*)d_in[2];
    const float* b0 = (const float*)d_in[3];
    const float* Ws = (const float*)d_in[4];
    const float* bs = (const float*)d_in[5];
    float* out = (float*)d_out;

    const int N = in_sizes[0] / 128;
    const int E = in_sizes[1] / 2;
    const int B = (N + BKN - 1) >> LB;   // 391 buckets for N=100k

    char* p = (char*)d_ws;
    auto carve = [&](size_t bytes) {
        char* r = p;
        p += (bytes + 255) & ~(size_t)255;
        return r;
    };
    int*      flag         = (int*)carve(4);
    int*      bucketCounts = (int*)carve(512 * 4);
    int*      bucketOffs   = (int*)carve(513 * 4);
    int*      bucketCursor = (int*)carve(512 * 4);
    unsigned* packed       = (unsigned*)carve((size_t)E * 4);
    int*      col          = (int*)carve((size_t)E * 4);
    int*      row_ptr      = (int*)carve((size_t)(N + 1) * 4);
    float*    dinv         = (float*)carve((size_t)N * 4);
    ushort_t* hs           = (ushort_t*)carve((size_t)N * 64 * 2);
    float*    xt           = (float*)carve((size_t)N * 64 * 4);   // f32 residual
    ushort_t* xtb          = (ushort_t*)carve((size_t)N * 64 * 2); // bf16 GEMM in
    ushort_t* hb           = (ushort_t*)carve((size_t)N * 64 * 2); // bf16 GEMM in

    hipMemsetAsync(flag, 1, 4, stream);              // nonzero = "int64"
    hipMemsetAsync(bucketCounts, 0, 512 * 4, stream);

    int dwords = min(2 * E, 65536);                  // sampled dtype probe
    detect64_kernel<<<(dwords + 255) / 256, 256, 0, stream>>>(
        (const unsigned int*)ei, dwords, flag);

    bucket_hist_kernel<<<512, 256, 0, stream>>>(ei, E, flag, bucketCounts, B);
    bucket_scan_kernel<<<1, 512, 0, stream>>>(bucketCounts, bucketOffs, bucketCursor, B);
    bucket_scatter_kernel<<<(E + CHUNK - 1) / CHUNK, 256, 0, stream>>>(
        ei, flag, bucketCursor, packed, E);
    sort_kernel<<<B, 256, 0, stream>>>(packed, bucketOffs, col, row_ptr, dinv, N, E);

    int gblocks = (N + 127) / 128;
    int ablocks = (N + 3) / 4;
    // layer 1: x_temp = agg(x @ W0) + b0            (no relu)
    gemm_mfma_kernel<128, true><<<gblocks, 256, 0, stream>>>(x, W0, dinv, hs, N);
    aggregate_kernel<<<ablocks, 256, 0, stream>>>(hs, dinv, b0, col, row_ptr,
                                                  nullptr, xt, xtb, N, 0);
    // layer 2: h = relu(agg(xt @ Ws[0]) + bs[0])    (bf16 only)
    gemm_mfma_kernel<64, false><<<gblocks, 256, 0, stream>>>(xtb, Ws, dinv, hs, N);
    aggregate_kernel<<<ablocks, 256, 0, stream>>>(hs, dinv, bs, col, row_ptr,
                                                  nullptr, nullptr, hb, N, 1);
    // layer 3: out = relu(agg(h @ Ws[1]) + bs[1]) + xt
    gemm_mfma_kernel<64, false><<<gblocks, 256, 0, stream>>>(hb, Ws + 64 * 64, dinv, hs, N);
    aggregate_kernel<<<ablocks, 256, 0, stream>>>(hs, dinv, bs + 64, col, row_ptr,
                                                  xt, out, nullptr, N, 1);
}